// Round 11
// baseline (414.556 us; speedup 1.0000x reference)
//
#include <hip/hip_runtime.h>

typedef unsigned short ushort_t;
typedef short s16x8 __attribute__((ext_vector_type(8)));
typedef float f32x4 __attribute__((ext_vector_type(4)));

#define LN_EPS 1e-5f

// ---- bf16 <-> f32 helpers ----
__device__ __forceinline__ float b2f(ushort_t u) {
    return __uint_as_float(((unsigned)u) << 16);
}
__device__ __forceinline__ ushort_t f2b(float f) {
    unsigned b = __float_as_uint(f);
    b += 0x7FFFu + ((b >> 16) & 1u);  // round-to-nearest-even
    return (ushort_t)(b >> 16);
}
__device__ __forceinline__ unsigned f2b2(float lo, float hi) {  // pack two bf16
    return (unsigned)f2b(lo) | ((unsigned)f2b(hi) << 16);
}
// dtype-flexible load: isF ? fp32 : bf16
__device__ __forceinline__ float ldf(const void* p, size_t i, int isF) {
    return isF ? ((const float*)p)[i] : b2f(((const ushort_t*)p)[i]);
}

// harness-compat symbol (unused)
__global__ void GraphSAGE_36026185678961_kernel() {}

// ---------------- dtype detect (block 0) + zero-init deg ----------------
// flags[0]=1 if float inputs fp32; flags[1]=1 if ints int64
__global__ void k_detect_zero(const void* w0, const void* ei, int* __restrict__ flags,
                              int* __restrict__ deg, int N) {
    int i = blockIdx.x * blockDim.x + threadIdx.x;
    if (i < N) deg[i] = 0;
    if (blockIdx.x == 0 && threadIdx.x < 64) {
        int t = threadIdx.x;
        const ushort_t* u = (const ushort_t*)w0;
        int pass = 0;
        #pragma unroll
        for (int k = 0; k < 4; ++k) {
            ushort_t v = u[t * 4 + k];
            int ex = (v >> 7) & 0xFF;
            if (ex == 0 || (ex >= 0x60 && ex <= 0x7E)) pass++;
        }
        const unsigned* w = (const unsigned*)ei;
        int nz = (w[2 * t + 1] != 0u) ? 1 : 0;
        #pragma unroll
        for (int off = 32; off; off >>= 1) {
            pass += __shfl_down(pass, off, 64);
            nz += __shfl_down(nz, off, 64);
        }
        if (t == 0) {
            flags[0] = (pass < 205) ? 1 : 0;
            flags[1] = (nz == 0) ? 1 : 0;
        }
    }
}

// ---------------- x -> bf16 conversion (layer-0 input) ----------------
__global__ void k_xconv(const void* X, const int* __restrict__ flags,
                        ushort_t* __restrict__ XB, int total4) {
    int idx = blockIdx.x * blockDim.x + threadIdx.x;
    if (idx >= total4) return;
    if (flags[0]) {
        float4 v = ((const float4*)X)[idx];
        ushort4 o;
        o.x = f2b(v.x); o.y = f2b(v.y); o.z = f2b(v.z); o.w = f2b(v.w);
        ((ushort4*)XB)[idx] = o;
    } else {
        ((ushort4*)XB)[idx] = ((const ushort4*)X)[idx];
    }
}

// ---------------- degree histogram (reads edge_index dst half directly) ----------------
__global__ void k_hist(const void* ei, int E, int N, const int* __restrict__ flags,
                       int* __restrict__ deg) {
    int e = blockIdx.x * blockDim.x + threadIdx.x;
    if (e >= E) return;
    int d = flags[1] ? (int)((const long long*)ei)[E + e] : ((const int*)ei)[E + e];
    if ((unsigned)d < (unsigned)N) atomicAdd(&deg[d], 1);
}

// hierarchical scan, phase 1: per-block (256-elem) exclusive scan + block totals
__global__ void k_scan1(const int* __restrict__ deg, int N,
                        int* __restrict__ rowptr, int* __restrict__ bsum) {
    __shared__ int wsum[4];
    __shared__ int wpre[4];
    int tid = threadIdx.x;
    int lane = tid & 63;
    int w = tid >> 6;
    int i = blockIdx.x * 256 + tid;
    int v = (i < N) ? deg[i] : 0;
    int x = v;
    #pragma unroll
    for (int off = 1; off < 64; off <<= 1) {
        int t = __shfl_up(x, off, 64);
        if (lane >= off) x += t;
    }
    if (lane == 63) wsum[w] = x;
    __syncthreads();
    if (tid == 0) {
        int a = wsum[0]; wpre[0] = a;
        a += wsum[1]; wpre[1] = a;
        a += wsum[2]; wpre[2] = a;
        a += wsum[3]; wpre[3] = a;
    }
    __syncthreads();
    int woff = (w == 0) ? 0 : wpre[w - 1];
    if (i < N) rowptr[i] = woff + x - v;  // block-local exclusive
    if (tid == 0) bsum[blockIdx.x] = wpre[3];
}

// phase 2: single-block exclusive scan of block sums + graph bounds (fused)
__global__ void k_scan2(const int* __restrict__ bsum, int nb,
                        int* __restrict__ boff, int* __restrict__ rowptrN,
                        const void* batch, int N, int G, const int* __restrict__ flags,
                        int* __restrict__ bounds) {
    __shared__ int wsum[4];
    __shared__ int wpre[4];
    int tid = threadIdx.x;
    int lane = tid & 63;
    int w = tid >> 6;
    int run = 0;
    for (int base = 0; base < nb; base += 256) {
        int i = base + tid;
        int v = (i < nb) ? bsum[i] : 0;
        int x = v;
        #pragma unroll
        for (int off = 1; off < 64; off <<= 1) {
            int t = __shfl_up(x, off, 64);
            if (lane >= off) x += t;
        }
        if (lane == 63) wsum[w] = x;
        __syncthreads();
        if (tid == 0) {
            int a = wsum[0]; wpre[0] = a;
            a += wsum[1]; wpre[1] = a;
            a += wsum[2]; wpre[2] = a;
            a += wsum[3]; wpre[3] = a;
        }
        __syncthreads();
        int woff = (w == 0) ? 0 : wpre[w - 1];
        if (i < nb) boff[i] = run + woff + x - v;
        int tot = wpre[3];
        __syncthreads();
        run += tot;
    }
    if (tid == 0) *rowptrN = run;  // rowptr[N] = E_total
    if (tid <= G) {
        int isL = flags[1];
        int lo = 0, hi = N;
        while (lo < hi) {
            int mid = (lo + hi) >> 1;
            int bv = isL ? (int)((const long long*)batch)[mid] : ((const int*)batch)[mid];
            if (bv < tid) lo = mid + 1; else hi = mid;
        }
        bounds[tid] = lo;
    }
}

// phase 3: add block offsets; produce cursor copy
__global__ void k_scan3(int* __restrict__ rowptr, const int* __restrict__ boff,
                        int* __restrict__ cursor, int N) {
    int i = blockIdx.x * 256 + threadIdx.x;
    if (i < N) {
        int r = rowptr[i] + boff[i >> 8];
        rowptr[i] = r;
        cursor[i] = r;
    }
}

// CSR fill (reads edge_index directly)
__global__ void k_fill(const void* ei, int E, int N, const int* __restrict__ flags,
                       int* __restrict__ cursor, int* __restrict__ col) {
    int e = blockIdx.x * blockDim.x + threadIdx.x;
    if (e >= E) return;
    int s, d;
    if (flags[1]) {
        const long long* p = (const long long*)ei;
        s = (int)p[e];
        d = (int)p[E + e];
    } else {
        const int* p = (const int*)ei;
        s = p[e];
        d = p[E + e];
    }
    if ((unsigned)d < (unsigned)N) {
        int p = atomicAdd(&cursor[d], 1);
        if ((unsigned)p < (unsigned)E) col[p] = ((unsigned)s < (unsigned)N) ? s : 0;
    }
}

// ---------------- mean aggregation: AGG[i] = mean_{j in N(i)} X[j]  (bf16, 128-wide) ----------------
// one wave per node; lane-quarter qn handles neighbor slot qn; lane loads uint4 = 8 bf16 (16B):
// one wave instruction gathers 4 neighbor rows; unroll x2 for 2 loads in flight.
__global__ __launch_bounds__(256) void k_agg(
    const ushort_t* __restrict__ X, const int* __restrict__ rowptr,
    const int* __restrict__ col, ushort_t* __restrict__ AGG, int N) {
    int i = blockIdx.x * 4 + (threadIdx.x >> 6);
    if (i >= N) return;
    int l = threadIdx.x & 63;
    int qn = l >> 4;   // neighbor slot 0..3
    int fo = l & 15;   // feature octet
    const uint4* X8 = (const uint4*)X;  // row = 16 uint4 groups
    int s = rowptr[i], e = rowptr[i + 1];
    float al[4] = {0.f, 0.f, 0.f, 0.f};
    float ah[4] = {0.f, 0.f, 0.f, 0.f};
    int p = s + qn;
    for (; p + 4 < e; p += 8) {
        int j0 = col[p], j1 = col[p + 4];
        uint4 u0 = X8[(size_t)j0 * 16 + fo];
        uint4 u1 = X8[(size_t)j1 * 16 + fo];
        unsigned w0[4] = {u0.x, u0.y, u0.z, u0.w};
        unsigned w1[4] = {u1.x, u1.y, u1.z, u1.w};
        #pragma unroll
        for (int k = 0; k < 4; ++k) {
            al[k] += __uint_as_float(w0[k] << 16) + __uint_as_float(w1[k] << 16);
            ah[k] += __uint_as_float(w0[k] & 0xFFFF0000u) + __uint_as_float(w1[k] & 0xFFFF0000u);
        }
    }
    for (; p < e; p += 4) {
        int j = col[p];
        uint4 u = X8[(size_t)j * 16 + fo];
        unsigned w0[4] = {u.x, u.y, u.z, u.w};
        #pragma unroll
        for (int k = 0; k < 4; ++k) {
            al[k] += __uint_as_float(w0[k] << 16);
            ah[k] += __uint_as_float(w0[k] & 0xFFFF0000u);
        }
    }
    #pragma unroll
    for (int k = 0; k < 4; ++k) {
        al[k] += __shfl_xor(al[k], 16, 64);
        al[k] += __shfl_xor(al[k], 32, 64);
        ah[k] += __shfl_xor(ah[k], 16, 64);
        ah[k] += __shfl_xor(ah[k], 32, 64);
    }
    if (qn == 0) {
        int d = e - s;
        float inv = 1.f / (float)(d > 0 ? d : 1);
        uint4 o;
        o.x = f2b2(al[0] * inv, ah[0] * inv);
        o.y = f2b2(al[1] * inv, ah[1] * inv);
        o.z = f2b2(al[2] * inv, ah[2] * inv);
        o.w = f2b2(al[3] * inv, ah[3] * inv);
        ((uint4*)AGG)[(size_t)i * 16 + fo] = o;
    }
}

// ---------------- weight prep (all 3 layers fused): Wb[f][k] bf16 ----------------
__global__ void k_wprep(const void* Wl0, const void* Wr0, const void* Wl1, const void* Wr1,
                        const void* Wl2, const void* Wr2, const int* __restrict__ flags,
                        ushort_t* __restrict__ Wb0, ushort_t* __restrict__ Wb1,
                        ushort_t* __restrict__ Wb2) {
    int t = blockIdx.x * blockDim.x + threadIdx.x;
    int isF = flags[0];
    const void* Wl;
    const void* Wr;
    ushort_t* Wb;
    int base;
    if (t < 256 * 128) { Wl = Wl0; Wr = Wr0; Wb = Wb0; base = t; }
    else if (t < 2 * 256 * 128) { Wl = Wl1; Wr = Wr1; Wb = Wb1; base = t - 256 * 128; }
    else if (t < 2 * 256 * 128 + 256 * 64) { Wl = Wl2; Wr = Wr2; Wb = Wb2; base = t - 2 * 256 * 128; }
    else return;
    int f = base >> 8, k = base & 255;
    float v = (k < 128) ? ldf(Wl, f * 128 + k, isF) : ldf(Wr, f * 128 + (k - 128), isF);
    Wb[base] = isF ? f2b(v) : ((const ushort_t*)((k < 128) ? Wl : Wr))[f * 128 + (k & 127)];
}

// ---------------- fused MFMA GEMM + bias + LayerNorm + ReLU ----------------
// One wave: R=2 row-tiles (32 rows) x FO cols; B-frag loaded once per (kk,nt), reused x2.
template <int FO>
__global__ __launch_bounds__(256, 2) void k_gemm_ln(
    const ushort_t* __restrict__ AGG, const ushort_t* __restrict__ X,
    const ushort_t* __restrict__ Wb,  // [FO][256] bf16
    const void* bl, const void* gam, const void* bet,
    const int* __restrict__ flags,
    ushort_t* __restrict__ H, int M) {
    constexpr int NT = FO / 16;
    constexpr int R = 2;
    int lane = threadIdx.x & 63;
    int wid = threadIdx.x >> 6;
    int wrow0 = (blockIdx.x * 4 + wid) * (R * 16);
    if (wrow0 >= M) return;
    int isF = flags[0];
    int m = lane & 15;
    int q = lane >> 4;

    int arow[R];
    #pragma unroll
    for (int r = 0; r < R; ++r) {
        int ar = wrow0 + r * 16 + m;
        arow[r] = (ar < M) ? ar : (M - 1);  // tail clamp; stores guarded below
    }

    f32x4 acc[R][NT];
    #pragma unroll
    for (int r = 0; r < R; ++r)
        #pragma unroll
        for (int nt = 0; nt < NT; ++nt) acc[r][nt] = (f32x4){0.f, 0.f, 0.f, 0.f};

    #pragma unroll
    for (int kk = 0; kk < 8; ++kk) {
        const ushort_t* base = (kk < 4) ? AGG : X;
        int ko = (kk & 3) * 32 + q * 8;
        s16x8 a[R];
        #pragma unroll
        for (int r = 0; r < R; ++r)
            a[r] = *(const s16x8*)(base + (size_t)arow[r] * 128 + ko);
        #pragma unroll
        for (int nt = 0; nt < NT; ++nt) {
            s16x8 b = *(const s16x8*)(Wb + (size_t)(nt * 16 + m) * 256 + kk * 32 + q * 8);
            #pragma unroll
            for (int r = 0; r < R; ++r)
                acc[r][nt] = __builtin_amdgcn_mfma_f32_16x16x32_bf16(a[r], b, acc[r][nt], 0, 0, 0);
        }
    }

    // epilogue per row-tile: bias + LN + ReLU + store
    #pragma unroll
    for (int r = 0; r < R; ++r) {
        #pragma unroll
        for (int nt = 0; nt < NT; ++nt) {
            float bv = ldf(bl, nt * 16 + m, isF);
            #pragma unroll
            for (int rr = 0; rr < 4; ++rr) acc[r][nt][rr] += bv;
        }
        float mu[4], rs[4];
        #pragma unroll
        for (int rr = 0; rr < 4; ++rr) {
            float s1 = 0.f, s2 = 0.f;
            #pragma unroll
            for (int nt = 0; nt < NT; ++nt) {
                float v = acc[r][nt][rr];
                s1 += v;
                s2 += v * v;
            }
            #pragma unroll
            for (int off = 1; off < 16; off <<= 1) {
                s1 += __shfl_xor(s1, off, 64);
                s2 += __shfl_xor(s2, off, 64);
            }
            float mm = s1 / (float)FO;
            float var = s2 / (float)FO - mm * mm;
            var = var > 0.f ? var : 0.f;
            mu[rr] = mm;
            rs[rr] = rsqrtf(var + LN_EPS);
        }
        #pragma unroll
        for (int nt = 0; nt < NT; ++nt) {
            int n0 = nt * 16 + m;
            float g = ldf(gam, n0, isF);
            float be = ldf(bet, n0, isF);
            #pragma unroll
            for (int rr = 0; rr < 4; ++rr) {
                int row = wrow0 + r * 16 + q * 4 + rr;
                if (row < M) {
                    float y = (acc[r][nt][rr] - mu[rr]) * rs[rr] * g + be;
                    y = y > 0.f ? y : 0.f;
                    H[(size_t)row * FO + n0] = f2b(y);
                }
            }
        }
    }
}

// ---------------- fused pooling + MLP (one block per graph) ----------------
__global__ __launch_bounds__(256) void k_pool_mlp(
    const ushort_t* __restrict__ H,  // [N,64], post-ReLU (>=0)
    const int* __restrict__ bounds,
    const void* cW1, const void* cb1, const void* cW2, const void* cb2,
    const int* __restrict__ flags, void* __restrict__ out, int N) {
    int g = blockIdx.x;
    int tid = threadIdx.x;
    int f = tid & 63;
    int sub = tid >> 6;  // 0..3
    int isF = flags[0];
    int s = bounds[g], e = bounds[g + 1];
    s = s < 0 ? 0 : (s > N ? N : s);
    e = e < s ? s : (e > N ? N : e);
    float sum = 0.f, mx = 0.f;  // H >= 0 so 0 is valid max identity
    for (int i = s + sub; i < e; i += 4) {
        float v = b2f(H[(size_t)i * 64 + f]);
        sum += v;
        mx = mx > v ? mx : v;
    }
    __shared__ float zs[4][64];
    __shared__ float zm[4][64];
    __shared__ float z[128];
    __shared__ float hid[128];
    __shared__ float r0[2], r1[2];
    zs[sub][f] = sum;
    zm[sub][f] = mx;
    __syncthreads();
    if (tid < 128) {
        if (tid < 64) {
            int cnt = e - s;
            float c = (float)(cnt > 0 ? cnt : 1);
            z[tid] = (zs[0][tid] + zs[1][tid] + zs[2][tid] + zs[3][tid]) / c;
        } else {
            int ff = tid - 64;
            float m0 = zm[0][ff] > zm[1][ff] ? zm[0][ff] : zm[1][ff];
            float m1 = zm[2][ff] > zm[3][ff] ? zm[2][ff] : zm[3][ff];
            z[tid] = m0 > m1 ? m0 : m1;
        }
    }
    __syncthreads();
    if (tid < 128) {
        float acc = ldf(cb1, tid, isF);
        #pragma unroll 8
        for (int k = 0; k < 128; ++k) acc += z[k] * ldf(cW1, tid * 128 + k, isF);
        hid[tid] = acc > 0.f ? acc : 0.f;
    }
    __syncthreads();
    if (tid < 128) {
        float p0 = hid[tid] * ldf(cW2, tid, isF);
        float p1 = hid[tid] * ldf(cW2, 128 + tid, isF);
        #pragma unroll
        for (int off = 32; off > 0; off >>= 1) {
            p0 += __shfl_xor(p0, off, 64);
            p1 += __shfl_xor(p1, off, 64);
        }
        if ((tid & 63) == 0) { r0[tid >> 6] = p0; r1[tid >> 6] = p1; }
    }
    __syncthreads();
    if (tid == 0) {
        float v0 = r0[0] + r0[1] + ldf(cb2, 0, isF);
        float v1 = r1[0] + r1[1] + ldf(cb2, 1, isF);
        if (isF) {
            ((float*)out)[g * 2 + 0] = v0;
            ((float*)out)[g * 2 + 1] = v1;
        } else {
            ((ushort_t*)out)[g * 2 + 0] = f2b(v0);
            ((ushort_t*)out)[g * 2 + 1] = f2b(v1);
        }
    }
}

// ---------------- launch ----------------
extern "C" void kernel_launch(void* const* d_in, const int* in_sizes, int n_in,
                              void* d_out, int out_size, void* d_ws, size_t ws_size,
                              hipStream_t stream) {
    const void* x = d_in[0];
    const void* ei = d_in[1];
    const void* batch = d_in[2];
    const void* Wl0 = d_in[3];
    const void* bl0 = d_in[4];
    const void* Wr0 = d_in[5];
    const void* g0 = d_in[6];
    const void* be0 = d_in[7];
    const void* Wl1 = d_in[8];
    const void* bl1 = d_in[9];
    const void* Wr1 = d_in[10];
    const void* g1 = d_in[11];
    const void* be1 = d_in[12];
    const void* Wl2 = d_in[13];
    const void* bl2 = d_in[14];
    const void* Wr2 = d_in[15];
    const void* g2 = d_in[16];
    const void* be2 = d_in[17];
    const void* cW1 = d_in[18];
    const void* cb1 = d_in[19];
    const void* cW2 = d_in[20];
    const void* cb2 = d_in[21];

    const int N = in_sizes[0] / 128;  // 50000
    const int E = in_sizes[1] / 2;    // 600000
    const int G = 64;

    // workspace carve-up (256B aligned slots)
    char* w = (char*)d_ws;
    size_t o = 0;
    auto take = [&](size_t bytes) -> void* {
        void* p = w + o;
        o = (o + bytes + 255) & ~(size_t)255;
        return p;
    };
    int nb1 = (N + 255) / 256;  // scan phase-1 blocks
    int* flags  = (int*)take(4 * 4);
    int* rowptr = (int*)take((size_t)(N + 1) * 4);
    int* cursor = (int*)take((size_t)N * 4);
    int* deg    = (int*)take((size_t)N * 4);
    int* bsum   = (int*)take((size_t)nb1 * 4);
    int* boff   = (int*)take((size_t)nb1 * 4);
    int* col    = (int*)take((size_t)E * 4);
    int* bounds = (int*)take((size_t)(G + 1) * 4);
    ushort_t* Wb0 = (ushort_t*)take((size_t)128 * 256 * 2);
    ushort_t* Wb1 = (ushort_t*)take((size_t)128 * 256 * 2);
    ushort_t* Wb2 = (ushort_t*)take((size_t)64 * 256 * 2);
    ushort_t* AGG = (ushort_t*)take((size_t)N * 128 * 2);
    ushort_t* H1  = (ushort_t*)take((size_t)N * 128 * 2);
    ushort_t* H2  = (ushort_t*)take((size_t)N * 128 * 2);
    ushort_t* XB  = H2;  // x-as-bf16 overlays H2: XB dead before H2 is first written
    ushort_t* H3  = H1;  // [N,64], reuses H1
    if (o > ws_size) return;  // ws too small -> zeros signature (diagnostic)

    int eb = (E + 255) / 256;
    k_detect_zero<<<nb1, 256, 0, stream>>>(Wl0, ei, flags, deg, N);
    k_xconv<<<(N * 128 / 4 + 255) / 256, 256, 0, stream>>>(x, flags, XB, N * 128 / 4);
    k_hist<<<eb, 256, 0, stream>>>(ei, E, N, flags, deg);
    k_scan1<<<nb1, 256, 0, stream>>>(deg, N, rowptr, bsum);
    k_scan2<<<1, 256, 0, stream>>>(bsum, nb1, boff, rowptr + N, batch, N, G, flags, bounds);
    k_scan3<<<nb1, 256, 0, stream>>>(rowptr, boff, cursor, N);
    k_fill<<<eb, 256, 0, stream>>>(ei, E, N, flags, cursor, col);
    k_wprep<<<(2 * 256 * 128 + 256 * 64 + 255) / 256, 256, 0, stream>>>(
        Wl0, Wr0, Wl1, Wr1, Wl2, Wr2, flags, Wb0, Wb1, Wb2);

    int gb = (N + 127) / 128;  // gemm blocks (4 waves x 32 rows)
    int ab = (N + 3) / 4;      // agg blocks (4 waves = 4 nodes each)

    // layer 0: XB -> H1
    k_agg<<<ab, 256, 0, stream>>>(XB, rowptr, col, AGG, N);
    k_gemm_ln<128><<<gb, 256, 0, stream>>>(AGG, XB, Wb0, bl0, g0, be0, flags, H1, N);
    // layer 1: H1 -> H2 (overwrites XB; XB dead)
    k_agg<<<ab, 256, 0, stream>>>(H1, rowptr, col, AGG, N);
    k_gemm_ln<128><<<gb, 256, 0, stream>>>(AGG, H1, Wb1, bl1, g1, be1, flags, H2, N);
    // layer 2: H2 -> H3 [N,64]
    k_agg<<<ab, 256, 0, stream>>>(H2, rowptr, col, AGG, N);
    k_gemm_ln<64><<<gb, 256, 0, stream>>>(AGG, H2, Wb2, bl2, g2, be2, flags, H3, N);

    k_pool_mlp<<<G, 256, 0, stream>>>(H3, bounds, cW1, cb1, cW2, cb2, flags, d_out, N);
}

// Round 12
// 376.782 us; speedup vs baseline: 1.1003x; 1.1003x over previous
//
#include <hip/hip_runtime.h>

typedef unsigned short ushort_t;
typedef short s16x8 __attribute__((ext_vector_type(8)));
typedef float f32x4 __attribute__((ext_vector_type(4)));

#define LN_EPS 1e-5f

// ---- bf16 <-> f32 helpers ----
__device__ __forceinline__ float b2f(ushort_t u) {
    return __uint_as_float(((unsigned)u) << 16);
}
__device__ __forceinline__ ushort_t f2b(float f) {
    unsigned b = __float_as_uint(f);
    b += 0x7FFFu + ((b >> 16) & 1u);  // round-to-nearest-even
    return (ushort_t)(b >> 16);
}
__device__ __forceinline__ unsigned f2b2(float lo, float hi) {  // pack two bf16
    return (unsigned)f2b(lo) | ((unsigned)f2b(hi) << 16);
}
// dtype-flexible load: isF ? fp32 : bf16
__device__ __forceinline__ float ldf(const void* p, size_t i, int isF) {
    return isF ? ((const float*)p)[i] : b2f(((const ushort_t*)p)[i]);
}

// harness-compat symbol (unused)
__global__ void GraphSAGE_36026185678961_kernel() {}

// ---------------- dtype detect (block 0) + zero-init deg, Z ----------------
// flags[0]=1 if float inputs fp32; flags[1]=1 if ints int64
__global__ void k_detect_zero(const void* w0, const void* ei, int* __restrict__ flags,
                              int* __restrict__ deg, float* __restrict__ Z, int N) {
    int i = blockIdx.x * blockDim.x + threadIdx.x;
    if (i < N) deg[i] = 0;
    if (i < 64 * 128) Z[i] = 0.f;
    if (blockIdx.x == 0 && threadIdx.x < 64) {
        int t = threadIdx.x;
        const ushort_t* u = (const ushort_t*)w0;
        int pass = 0;
        #pragma unroll
        for (int k = 0; k < 4; ++k) {
            ushort_t v = u[t * 4 + k];
            int ex = (v >> 7) & 0xFF;
            if (ex == 0 || (ex >= 0x60 && ex <= 0x7E)) pass++;
        }
        const unsigned* w = (const unsigned*)ei;
        int nz = (w[2 * t + 1] != 0u) ? 1 : 0;
        #pragma unroll
        for (int off = 32; off; off >>= 1) {
            pass += __shfl_down(pass, off, 64);
            nz += __shfl_down(nz, off, 64);
        }
        if (t == 0) {
            flags[0] = (pass < 205) ? 1 : 0;
            flags[1] = (nz == 0) ? 1 : 0;
        }
    }
}

// ---------------- x -> bf16 conversion (layer-0 input) ----------------
__global__ void k_xconv(const void* X, const int* __restrict__ flags,
                        ushort_t* __restrict__ XB, int total4) {
    int idx = blockIdx.x * blockDim.x + threadIdx.x;
    if (idx >= total4) return;
    if (flags[0]) {
        float4 v = ((const float4*)X)[idx];
        ushort4 o;
        o.x = f2b(v.x); o.y = f2b(v.y); o.z = f2b(v.z); o.w = f2b(v.w);
        ((ushort4*)XB)[idx] = o;
    } else {
        ((ushort4*)XB)[idx] = ((const ushort4*)X)[idx];
    }
}

// ---------------- degree histogram (reads edge_index dst half directly) ----------------
__global__ void k_hist(const void* ei, int E, int N, const int* __restrict__ flags,
                       int* __restrict__ deg) {
    int e = blockIdx.x * blockDim.x + threadIdx.x;
    if (e >= E) return;
    int d = flags[1] ? (int)((const long long*)ei)[E + e] : ((const int*)ei)[E + e];
    if ((unsigned)d < (unsigned)N) atomicAdd(&deg[d], 1);
}

// hierarchical scan, phase 1
__global__ void k_scan1(const int* __restrict__ deg, int N,
                        int* __restrict__ rowptr, int* __restrict__ bsum) {
    __shared__ int wsum[4];
    __shared__ int wpre[4];
    int tid = threadIdx.x;
    int lane = tid & 63;
    int w = tid >> 6;
    int i = blockIdx.x * 256 + tid;
    int v = (i < N) ? deg[i] : 0;
    int x = v;
    #pragma unroll
    for (int off = 1; off < 64; off <<= 1) {
        int t = __shfl_up(x, off, 64);
        if (lane >= off) x += t;
    }
    if (lane == 63) wsum[w] = x;
    __syncthreads();
    if (tid == 0) {
        int a = wsum[0]; wpre[0] = a;
        a += wsum[1]; wpre[1] = a;
        a += wsum[2]; wpre[2] = a;
        a += wsum[3]; wpre[3] = a;
    }
    __syncthreads();
    int woff = (w == 0) ? 0 : wpre[w - 1];
    if (i < N) rowptr[i] = woff + x - v;
    if (tid == 0) bsum[blockIdx.x] = wpre[3];
}

// phase 2: scan of block sums + graph bounds (fused)
__global__ void k_scan2(const int* __restrict__ bsum, int nb,
                        int* __restrict__ boff, int* __restrict__ rowptrN,
                        const void* batch, int N, int G, const int* __restrict__ flags,
                        int* __restrict__ bounds) {
    __shared__ int wsum[4];
    __shared__ int wpre[4];
    int tid = threadIdx.x;
    int lane = tid & 63;
    int w = tid >> 6;
    int run = 0;
    for (int base = 0; base < nb; base += 256) {
        int i = base + tid;
        int v = (i < nb) ? bsum[i] : 0;
        int x = v;
        #pragma unroll
        for (int off = 1; off < 64; off <<= 1) {
            int t = __shfl_up(x, off, 64);
            if (lane >= off) x += t;
        }
        if (lane == 63) wsum[w] = x;
        __syncthreads();
        if (tid == 0) {
            int a = wsum[0]; wpre[0] = a;
            a += wsum[1]; wpre[1] = a;
            a += wsum[2]; wpre[2] = a;
            a += wsum[3]; wpre[3] = a;
        }
        __syncthreads();
        int woff = (w == 0) ? 0 : wpre[w - 1];
        if (i < nb) boff[i] = run + woff + x - v;
        int tot = wpre[3];
        __syncthreads();
        run += tot;
    }
    if (tid == 0) *rowptrN = run;
    if (tid <= G) {
        int isL = flags[1];
        int lo = 0, hi = N;
        while (lo < hi) {
            int mid = (lo + hi) >> 1;
            int bv = isL ? (int)((const long long*)batch)[mid] : ((const int*)batch)[mid];
            if (bv < tid) lo = mid + 1; else hi = mid;
        }
        bounds[tid] = lo;
    }
}

// phase 3
__global__ void k_scan3(int* __restrict__ rowptr, const int* __restrict__ boff,
                        int* __restrict__ cursor, int N) {
    int i = blockIdx.x * 256 + threadIdx.x;
    if (i < N) {
        int r = rowptr[i] + boff[i >> 8];
        rowptr[i] = r;
        cursor[i] = r;
    }
}

// CSR fill (reads edge_index directly)
__global__ void k_fill(const void* ei, int E, int N, const int* __restrict__ flags,
                       int* __restrict__ cursor, int* __restrict__ col) {
    int e = blockIdx.x * blockDim.x + threadIdx.x;
    if (e >= E) return;
    int s, d;
    if (flags[1]) {
        const long long* p = (const long long*)ei;
        s = (int)p[e];
        d = (int)p[E + e];
    } else {
        const int* p = (const int*)ei;
        s = p[e];
        d = p[E + e];
    }
    if ((unsigned)d < (unsigned)N) {
        int p = atomicAdd(&cursor[d], 1);
        if ((unsigned)p < (unsigned)E) col[p] = ((unsigned)s < (unsigned)N) ? s : 0;
    }
}

// ---------------- mean aggregation: AGG[i] = mean_{j in N(i)} X[j]  (bf16, 128-wide) ----------------
__global__ __launch_bounds__(256) void k_agg(
    const ushort_t* __restrict__ X, const int* __restrict__ rowptr,
    const int* __restrict__ col, ushort_t* __restrict__ AGG, int N) {
    int i = blockIdx.x * 4 + (threadIdx.x >> 6);
    if (i >= N) return;
    int l = threadIdx.x & 63;
    int qn = l >> 4;   // neighbor slot 0..3
    int fo = l & 15;   // feature octet
    const uint4* X8 = (const uint4*)X;  // row = 16 uint4 groups
    int s = rowptr[i], e = rowptr[i + 1];
    float al[4] = {0.f, 0.f, 0.f, 0.f};
    float ah[4] = {0.f, 0.f, 0.f, 0.f};
    int p = s + qn;
    for (; p + 4 < e; p += 8) {
        int j0 = col[p], j1 = col[p + 4];
        uint4 u0 = X8[(size_t)j0 * 16 + fo];
        uint4 u1 = X8[(size_t)j1 * 16 + fo];
        unsigned w0[4] = {u0.x, u0.y, u0.z, u0.w};
        unsigned w1[4] = {u1.x, u1.y, u1.z, u1.w};
        #pragma unroll
        for (int k = 0; k < 4; ++k) {
            al[k] += __uint_as_float(w0[k] << 16) + __uint_as_float(w1[k] << 16);
            ah[k] += __uint_as_float(w0[k] & 0xFFFF0000u) + __uint_as_float(w1[k] & 0xFFFF0000u);
        }
    }
    for (; p < e; p += 4) {
        int j = col[p];
        uint4 u = X8[(size_t)j * 16 + fo];
        unsigned w0[4] = {u.x, u.y, u.z, u.w};
        #pragma unroll
        for (int k = 0; k < 4; ++k) {
            al[k] += __uint_as_float(w0[k] << 16);
            ah[k] += __uint_as_float(w0[k] & 0xFFFF0000u);
        }
    }
    #pragma unroll
    for (int k = 0; k < 4; ++k) {
        al[k] += __shfl_xor(al[k], 16, 64);
        al[k] += __shfl_xor(al[k], 32, 64);
        ah[k] += __shfl_xor(ah[k], 16, 64);
        ah[k] += __shfl_xor(ah[k], 32, 64);
    }
    if (qn == 0) {
        int d = e - s;
        float inv = 1.f / (float)(d > 0 ? d : 1);
        uint4 o;
        o.x = f2b2(al[0] * inv, ah[0] * inv);
        o.y = f2b2(al[1] * inv, ah[1] * inv);
        o.z = f2b2(al[2] * inv, ah[2] * inv);
        o.w = f2b2(al[3] * inv, ah[3] * inv);
        ((uint4*)AGG)[(size_t)i * 16 + fo] = o;
    }
}

// ---------------- weight prep (all 3 layers fused): Wb[f][k] bf16 ----------------
__global__ void k_wprep(const void* Wl0, const void* Wr0, const void* Wl1, const void* Wr1,
                        const void* Wl2, const void* Wr2, const int* __restrict__ flags,
                        ushort_t* __restrict__ Wb0, ushort_t* __restrict__ Wb1,
                        ushort_t* __restrict__ Wb2) {
    int t = blockIdx.x * blockDim.x + threadIdx.x;
    int isF = flags[0];
    const void* Wl;
    const void* Wr;
    ushort_t* Wb;
    int base;
    if (t < 256 * 128) { Wl = Wl0; Wr = Wr0; Wb = Wb0; base = t; }
    else if (t < 2 * 256 * 128) { Wl = Wl1; Wr = Wr1; Wb = Wb1; base = t - 256 * 128; }
    else if (t < 2 * 256 * 128 + 256 * 64) { Wl = Wl2; Wr = Wr2; Wb = Wb2; base = t - 2 * 256 * 128; }
    else return;
    int f = base >> 8, k = base & 255;
    float v = (k < 128) ? ldf(Wl, f * 128 + k, isF) : ldf(Wr, f * 128 + (k - 128), isF);
    Wb[base] = isF ? f2b(v) : ((const ushort_t*)((k < 128) ? Wl : Wr))[f * 128 + (k & 127)];
}

// ---------------- fused MFMA GEMM + bias + LayerNorm + ReLU ----------------
// One wave: R=2 row-tiles (32 rows) x FO cols; B-frag loaded once per (kk,nt), reused x2.
template <int FO>
__global__ __launch_bounds__(256, 2) void k_gemm_ln(
    const ushort_t* __restrict__ AGG, const ushort_t* __restrict__ X,
    const ushort_t* __restrict__ Wb,  // [FO][256] bf16
    const void* bl, const void* gam, const void* bet,
    const int* __restrict__ flags,
    ushort_t* __restrict__ H, int M) {
    constexpr int NT = FO / 16;
    constexpr int R = 2;
    int lane = threadIdx.x & 63;
    int wid = threadIdx.x >> 6;
    int wrow0 = (blockIdx.x * 4 + wid) * (R * 16);
    if (wrow0 >= M) return;
    int isF = flags[0];
    int m = lane & 15;
    int q = lane >> 4;

    int arow[R];
    #pragma unroll
    for (int r = 0; r < R; ++r) {
        int ar = wrow0 + r * 16 + m;
        arow[r] = (ar < M) ? ar : (M - 1);  // tail clamp; stores guarded below
    }

    f32x4 acc[R][NT];
    #pragma unroll
    for (int r = 0; r < R; ++r)
        #pragma unroll
        for (int nt = 0; nt < NT; ++nt) acc[r][nt] = (f32x4){0.f, 0.f, 0.f, 0.f};

    #pragma unroll
    for (int kk = 0; kk < 8; ++kk) {
        const ushort_t* base = (kk < 4) ? AGG : X;
        int ko = (kk & 3) * 32 + q * 8;
        s16x8 a[R];
        #pragma unroll
        for (int r = 0; r < R; ++r)
            a[r] = *(const s16x8*)(base + (size_t)arow[r] * 128 + ko);
        #pragma unroll
        for (int nt = 0; nt < NT; ++nt) {
            s16x8 b = *(const s16x8*)(Wb + (size_t)(nt * 16 + m) * 256 + kk * 32 + q * 8);
            #pragma unroll
            for (int r = 0; r < R; ++r)
                acc[r][nt] = __builtin_amdgcn_mfma_f32_16x16x32_bf16(a[r], b, acc[r][nt], 0, 0, 0);
        }
    }

    #pragma unroll
    for (int r = 0; r < R; ++r) {
        #pragma unroll
        for (int nt = 0; nt < NT; ++nt) {
            float bv = ldf(bl, nt * 16 + m, isF);
            #pragma unroll
            for (int rr = 0; rr < 4; ++rr) acc[r][nt][rr] += bv;
        }
        float mu[4], rs[4];
        #pragma unroll
        for (int rr = 0; rr < 4; ++rr) {
            float s1 = 0.f, s2 = 0.f;
            #pragma unroll
            for (int nt = 0; nt < NT; ++nt) {
                float v = acc[r][nt][rr];
                s1 += v;
                s2 += v * v;
            }
            #pragma unroll
            for (int off = 1; off < 16; off <<= 1) {
                s1 += __shfl_xor(s1, off, 64);
                s2 += __shfl_xor(s2, off, 64);
            }
            float mm = s1 / (float)FO;
            float var = s2 / (float)FO - mm * mm;
            var = var > 0.f ? var : 0.f;
            mu[rr] = mm;
            rs[rr] = rsqrtf(var + LN_EPS);
        }
        #pragma unroll
        for (int nt = 0; nt < NT; ++nt) {
            int n0 = nt * 16 + m;
            float g = ldf(gam, n0, isF);
            float be = ldf(bet, n0, isF);
            #pragma unroll
            for (int rr = 0; rr < 4; ++rr) {
                int row = wrow0 + r * 16 + q * 4 + rr;
                if (row < M) {
                    float y = (acc[r][nt][rr] - mu[rr]) * rs[rr] * g + be;
                    y = y > 0.f ? y : 0.f;
                    H[(size_t)row * FO + n0] = f2b(y);
                }
            }
        }
    }
}

// ---------------- pooling: Z[64][128]: cols 0..63 sum, 64..127 max ----------------
// grid = G*16 blocks; 256 threads; lane handles 2 packed feats (uint load);
// 8 row-streams per block x 16 chunks = 128 streams per graph.
__global__ __launch_bounds__(256) void k_pool(
    const ushort_t* __restrict__ H,  // [N,64], post-ReLU (>=0)
    const int* __restrict__ bounds, float* __restrict__ Z, int N) {
    int g = blockIdx.x >> 4;
    int chunk = blockIdx.x & 15;
    int lane = threadIdx.x & 31;   // feature pair index: feats 2*lane, 2*lane+1
    int sub = threadIdx.x >> 5;    // 0..7
    int strm = chunk * 8 + sub;    // 0..127
    int s = bounds[g], e = bounds[g + 1];
    s = s < 0 ? 0 : (s > N ? N : s);
    e = e < s ? s : (e > N ? N : e);
    const unsigned* H2 = (const unsigned*)H;  // row = 32 uints
    float sl = 0.f, sh = 0.f, ml = 0.f, mh = 0.f;  // H >= 0: 0 is valid max identity
    for (int i = s + strm; i < e; i += 128) {
        unsigned u = H2[(size_t)i * 32 + lane];
        float vl = __uint_as_float(u << 16);
        float vh = __uint_as_float(u & 0xFFFF0000u);
        sl += vl; sh += vh;
        ml = ml > vl ? ml : vl;
        mh = mh > vh ? mh : vh;
    }
    int f0 = lane * 2;
    atomicAdd(&Z[g * 128 + f0], sl);
    atomicAdd(&Z[g * 128 + f0 + 1], sh);
    atomicMax((int*)&Z[g * 128 + 64 + f0], __float_as_int(ml));
    atomicMax((int*)&Z[g * 128 + 64 + f0 + 1], __float_as_int(mh));
}

// ---------------- final MLP; output dtype follows flags[0] ----------------
__global__ void k_mlp(const float* __restrict__ Z, const int* __restrict__ bounds,
                      const void* cW1, const void* cb1, const void* cW2, const void* cb2,
                      const int* __restrict__ flags, void* __restrict__ out) {
    int g = blockIdx.x;
    int f = threadIdx.x;  // 0..127
    int isF = flags[0];
    __shared__ float z[128];
    __shared__ float hid[128];
    __shared__ float r0[2], r1[2];
    int cnt = bounds[g + 1] - bounds[g];
    float c = (float)(cnt > 0 ? cnt : 1);
    float zv = Z[g * 128 + f];
    if (f < 64) zv /= c;
    z[f] = zv;
    __syncthreads();
    float acc = ldf(cb1, f, isF);
    #pragma unroll 8
    for (int k = 0; k < 128; ++k) acc += z[k] * ldf(cW1, f * 128 + k, isF);
    acc = acc > 0.f ? acc : 0.f;
    hid[f] = acc;
    __syncthreads();
    float p0 = hid[f] * ldf(cW2, f, isF);
    float p1 = hid[f] * ldf(cW2, 128 + f, isF);
    #pragma unroll
    for (int off = 32; off > 0; off >>= 1) {
        p0 += __shfl_xor(p0, off, 64);
        p1 += __shfl_xor(p1, off, 64);
    }
    int w = f >> 6;
    if ((f & 63) == 0) { r0[w] = p0; r1[w] = p1; }
    __syncthreads();
    if (f == 0) {
        float v0 = r0[0] + r0[1] + ldf(cb2, 0, isF);
        float v1 = r1[0] + r1[1] + ldf(cb2, 1, isF);
        if (isF) {
            ((float*)out)[g * 2 + 0] = v0;
            ((float*)out)[g * 2 + 1] = v1;
        } else {
            ((ushort_t*)out)[g * 2 + 0] = f2b(v0);
            ((ushort_t*)out)[g * 2 + 1] = f2b(v1);
        }
    }
}

// ---------------- launch ----------------
extern "C" void kernel_launch(void* const* d_in, const int* in_sizes, int n_in,
                              void* d_out, int out_size, void* d_ws, size_t ws_size,
                              hipStream_t stream) {
    const void* x = d_in[0];
    const void* ei = d_in[1];
    const void* batch = d_in[2];
    const void* Wl0 = d_in[3];
    const void* bl0 = d_in[4];
    const void* Wr0 = d_in[5];
    const void* g0 = d_in[6];
    const void* be0 = d_in[7];
    const void* Wl1 = d_in[8];
    const void* bl1 = d_in[9];
    const void* Wr1 = d_in[10];
    const void* g1 = d_in[11];
    const void* be1 = d_in[12];
    const void* Wl2 = d_in[13];
    const void* bl2 = d_in[14];
    const void* Wr2 = d_in[15];
    const void* g2 = d_in[16];
    const void* be2 = d_in[17];
    const void* cW1 = d_in[18];
    const void* cb1 = d_in[19];
    const void* cW2 = d_in[20];
    const void* cb2 = d_in[21];

    const int N = in_sizes[0] / 128;  // 50000
    const int E = in_sizes[1] / 2;    // 600000
    const int G = 64;

    // workspace carve-up (256B aligned slots)
    char* w = (char*)d_ws;
    size_t o = 0;
    auto take = [&](size_t bytes) -> void* {
        void* p = w + o;
        o = (o + bytes + 255) & ~(size_t)255;
        return p;
    };
    int nb1 = (N + 255) / 256;  // scan phase-1 blocks
    int* flags  = (int*)take(4 * 4);
    int* rowptr = (int*)take((size_t)(N + 1) * 4);
    int* cursor = (int*)take((size_t)N * 4);
    int* deg    = (int*)take((size_t)N * 4);
    int* bsum   = (int*)take((size_t)nb1 * 4);
    int* boff   = (int*)take((size_t)nb1 * 4);
    int* col    = (int*)take((size_t)E * 4);
    int* bounds = (int*)take((size_t)(G + 1) * 4);
    float* Z    = (float*)take((size_t)G * 128 * 4);
    ushort_t* Wb0 = (ushort_t*)take((size_t)128 * 256 * 2);
    ushort_t* Wb1 = (ushort_t*)take((size_t)128 * 256 * 2);
    ushort_t* Wb2 = (ushort_t*)take((size_t)64 * 256 * 2);
    ushort_t* AGG = (ushort_t*)take((size_t)N * 128 * 2);
    ushort_t* H1  = (ushort_t*)take((size_t)N * 128 * 2);
    ushort_t* H2  = (ushort_t*)take((size_t)N * 128 * 2);
    ushort_t* XB  = H2;  // x-as-bf16 overlays H2: XB dead before H2 is first written
    ushort_t* H3  = H1;  // [N,64], reuses H1
    if (o > ws_size) return;  // ws too small -> zeros signature (diagnostic)

    int eb = (E + 255) / 256;
    k_detect_zero<<<nb1, 256, 0, stream>>>(Wl0, ei, flags, deg, Z, N);
    k_xconv<<<(N * 128 / 4 + 255) / 256, 256, 0, stream>>>(x, flags, XB, N * 128 / 4);
    k_hist<<<eb, 256, 0, stream>>>(ei, E, N, flags, deg);
    k_scan1<<<nb1, 256, 0, stream>>>(deg, N, rowptr, bsum);
    k_scan2<<<1, 256, 0, stream>>>(bsum, nb1, boff, rowptr + N, batch, N, G, flags, bounds);
    k_scan3<<<nb1, 256, 0, stream>>>(rowptr, boff, cursor, N);
    k_fill<<<eb, 256, 0, stream>>>(ei, E, N, flags, cursor, col);
    k_wprep<<<(2 * 256 * 128 + 256 * 64 + 255) / 256, 256, 0, stream>>>(
        Wl0, Wr0, Wl1, Wr1, Wl2, Wr2, flags, Wb0, Wb1, Wb2);

    int gb = (N + 127) / 128;  // gemm blocks (4 waves x 32 rows)
    int ab = (N + 3) / 4;      // agg blocks (4 waves = 4 nodes each)

    // layer 0: XB -> H1
    k_agg<<<ab, 256, 0, stream>>>(XB, rowptr, col, AGG, N);
    k_gemm_ln<128><<<gb, 256, 0, stream>>>(AGG, XB, Wb0, bl0, g0, be0, flags, H1, N);
    // layer 1: H1 -> H2 (overwrites XB; XB dead)
    k_agg<<<ab, 256, 0, stream>>>(H1, rowptr, col, AGG, N);
    k_gemm_ln<128><<<gb, 256, 0, stream>>>(AGG, H1, Wb1, bl1, g1, be1, flags, H2, N);
    // layer 2: H2 -> H3 [N,64]
    k_agg<<<ab, 256, 0, stream>>>(H2, rowptr, col, AGG, N);
    k_gemm_ln<64><<<gb, 256, 0, stream>>>(AGG, H2, Wb2, bl2, g2, be2, flags, H3, N);

    k_pool<<<G * 16, 256, 0, stream>>>(H3, bounds, Z, N);
    k_mlp<<<G, 128, 0, stream>>>(Z, bounds, cW1, cb1, cW2, cb2, flags, d_out);
}